// Round 15
// baseline (13144.682 us; speedup 1.0000x reference)
//
#include <hip/hip_runtime.h>
#include <stdint.h>

// Problem: D-FPS. points_xyz (16, 131072, 3) fp32 -> indices (16, 4096) int32.
//
// Round 15 = round 14 structure (best: 8832 us) with CO-RESIDENT BLOCK PAIRS:
// NBLK 16->32, TPB 1024->512, LDS 98->48 KB => 512 blocks = 2 blocks/CU.
// While one block's w0 spins on the gs poll (and its waves sit at barrier2),
// the co-resident block's waves own the CU (m114: MFMA/VALU waves co-schedule
// fully). This hides the ~1 us publish->poll RT under the neighbor's update
// WITHOUT putting two batches in one program-order chain (r12's mistake).
// b = (blk>>5)&15 so co-residents (blkIdx +-256 under linear dispatch) come
// from different batches (independent sync chains).
//
// Locked-in lessons (r2-r14):
//  - relaxed-only AGENT atomics; tag+payload in one 64-bit word (r7/r8).
//  - ONE relaxed polling wave per block (r5/r10).
//  - hardware barrier beats software tag-spin intra-block (r13/r14).
//  - points in LDS SoA (r3-r5); FMA-chain distance, exact-rounded subs (r2).
//  - removals/overlap help; rearrangements and added chain work regress.

#define BATCH 16
#define NPTS  131072
#define NSAMP 4096
#define NBLK  32                  // blocks per batch
#define TPB   512                 // 8 waves
#define CHUNK (NPTS / NBLK)       // 4096 points per block
#define PPT   (CHUNK / TPB)       // 8 points per thread
#define NWAVE (TPB / 64)          // 8

typedef unsigned long long u64;
typedef unsigned int u32;

// Global slot word (8B, one per block per parity):
//   [63:32] dist bits (>=0 -> monotone) | [31:15] idx (17b) | [14:0] iter tag
// Poison 0xAA.. -> tag 0x2AAA; zero-init -> tag 0; live tags are 1..4095.
// Ring-2 by parity; ordering via the value-dependence chain (r8-proven).

__global__ void fps_init_kernel(u64* __restrict__ ws) {
    int i = blockIdx.x * blockDim.x + threadIdx.x;
    if (i < BATCH * 2 * NBLK) ws[i] = 0ull;   // 1024 words
}

__global__ __launch_bounds__(TPB, 4) void fps_kernel(
        const float* __restrict__ xyz, int* __restrict__ out,
        u64* __restrict__ gslot) {
    const int blk   = blockIdx.x;
    const int b     = (blk >> 5) & 15;  // co-residents (+-256) differ in batch
    const int chunk = blk & 31;
    const int tid   = threadIdx.x;
    const int w     = tid >> 6;
    const int lane  = tid & 63;

    const float* bxyz = xyz + (size_t)b * NPTS * 3;
    const int base = chunk * CHUNK;

    // ---- LDS: SoA points + plain red keys + plain bc (~48.2 KB) ----
    __shared__ float2 sxy[CHUNK];          // 32 KB
    __shared__ float  szz[CHUNK];          // 16 KB
    __shared__ u64 red[NWAVE];
    __shared__ u32 bc;                     // winning index, barrier-ordered
    for (int i = tid; i < CHUNK; i += TPB) {
        size_t p = (size_t)(base + i) * 3;
        sxy[i] = make_float2(bxyz[p + 0], bxyz[p + 1]);
        szz[i] = bxyz[p + 2];
    }
    if (tid == 0 && chunk == 0) out[b * NSAMP] = 0; // iter 0 emits index 0
    __syncthreads();   // staging visibility

    float pd[PPT];
#pragma unroll
    for (int k = 0; k < PPT; ++k) pd[k] = __builtin_inff();

    float cx = bxyz[0], cy = bxyz[1], cz = bxyz[2];

    u64* gs = gslot + (size_t)b * 2 * NBLK;   // [2][NBLK]

    for (int it = 1; it < NSAMP; ++it) {
        const int par = it & 1;
        u64* gsp = gs + par * NBLK;

        // ---- update min-dists + local argmax (LDS + registers) ----
        // Verified arithmetic (round 2, absmax 0): FMA-contracted
        //   d = fma(dz,dz, fma(dy,dy, dx*dx)), subs exact-rounded.
        float bd = -1.0f;
        int   bk = 0;
#pragma unroll
        for (int k = 0; k < PPT; ++k) {
            int i = tid + TPB * k;
            float2 xy = sxy[i];
            float  z  = szz[i];
            float dx = __fsub_rn(xy.x, cx);
            float dy = __fsub_rn(xy.y, cy);
            float dz = __fsub_rn(z,    cz);
            float d  = __builtin_fmaf(dz, dz,
                         __builtin_fmaf(dy, dy, __fmul_rn(dx, dx)));
            float nd = fminf(pd[k], d);
            pd[k] = nd;
            // strict >: earliest k wins (gi ascends with k) = first-occurrence
            if (nd > bd) { bd = nd; bk = k; }
        }
        u32 gi = (u32)(base + tid + TPB * bk);
        u64 key = ((u64)__float_as_uint(bd) << 32) | (u64)(~gi);

        // ---- wave butterfly (max dist, then min index) ----
#pragma unroll
        for (int off = 1; off <= 32; off <<= 1) {
            u64 o = __shfl_xor(key, off, 64);
            key = key > o ? key : o;
        }
        if (lane == 0) red[w] = key;      // plain store; barrier1 orders it
        __syncthreads();                   // barrier1

        if (w == 0) {
            // ---- combine 8 plain keys (real keys > 0; lanes 8+ feed 0) ----
            u64 k2 = (lane < NWAVE) ? red[lane] : 0ull;
#pragma unroll
            for (int off = 1; off <= 4; off <<= 1) {
                u64 o = __shfl_xor(k2, off, 64);
                k2 = k2 > o ? k2 : o;
            }
            // ---- ONE relaxed agent store publishes the block winner ----
            if (lane == 0) {
                u32 db  = (u32)(k2 >> 32);
                u32 idx = ~(u32)k2;        // = gi (fits 17 bits)
                __hip_atomic_store(&gsp[chunk],
                                   ((u64)db << 32) | ((u64)idx << 15) | (u64)it,
                                   __ATOMIC_RELAXED, __HIP_MEMORY_SCOPE_AGENT);
            }
            // ---- relaxed poll of the 32 slot words ----
            u64 v; bool ok;
            do {
                v  = (lane < NBLK)
                       ? __hip_atomic_load(&gsp[lane], __ATOMIC_RELAXED,
                                           __HIP_MEMORY_SCOPE_AGENT)
                       : 0ull;
                ok = (lane < NBLK) ? ((v & 0x7FFFull) == (u64)it) : true;
            } while (__ballot(ok) != ~0ull);
            u64 k3 = 0ull;
            if (lane < NBLK) {
                u32 db  = (u32)(v >> 32);
                u32 idx = (u32)((v >> 15) & 0x1FFFFu);
                k3 = ((u64)db << 32) | (u64)(~idx);
            }
            // 5-step butterfly over lanes 0..31 (closed hypercube) + broadcast
#pragma unroll
            for (int off = 1; off <= 16; off <<= 1) {
                u64 o = __shfl_xor(k3, off, 64);
                k3 = k3 > o ? k3 : o;
            }
            k3 = __shfl(k3, 0, 64);
            u32 widx = ~(u32)k3;
            if (lane == 0) {
                if (chunk == 0) out[b * NSAMP + it] = (int)widx;
                bc = widx;                 // plain store; barrier2 orders it
            }
        }
        __syncthreads();                   // barrier2

        u32 widx = bc;                     // barrier-ordered plain read
        cx = bxyz[3 * (size_t)widx + 0];   // same-address broadcast load
        cy = bxyz[3 * (size_t)widx + 1];
        cz = bxyz[3 * (size_t)widx + 2];
    }
}

extern "C" void kernel_launch(void* const* d_in, const int* in_sizes, int n_in,
                              void* d_out, int out_size, void* d_ws, size_t ws_size,
                              hipStream_t stream) {
    const float* xyz = (const float*)d_in[0];
    int* out = (int*)d_out;
    u64* gslot = (u64*)d_ws;   // [BATCH][2][NBLK] u64 = 8 KB

    hipLaunchKernelGGL(fps_init_kernel, dim3(4), dim3(256), 0, stream, gslot);
    hipLaunchKernelGGL(fps_kernel, dim3(BATCH * NBLK), dim3(TPB), 0, stream,
                       xyz, out, gslot);
}

// Round 16
// 8838.868 us; speedup vs baseline: 1.4871x; 1.4871x over previous
//
#include <hip/hip_runtime.h>
#include <stdint.h>

// Problem: D-FPS. points_xyz (16, 131072, 3) fp32 -> indices (16, 4096) int32.
//
// Round 16 = round 14 VERBATIM RESTORATION (best: 8832 us). r15's co-resident
// pairs regressed (FETCH 20->251 MB: 512 pollers x 2x slots; skew over 32
// blocks) — confirming the r14 topology as the measured optimum:
//   16 blocks/batch, TPB=1024, ONE relaxed polling wave per block,
//   barriers (not tag-spins) intra-block, relaxed tagged single-word gs.
//
// Final chain model (2.16 us/iter, latency-bound):
//   update ~0.45 (LDS-BW) + butterfly/barrier1/combine ~0.35 +
//   publish->poll agent RT ~0.6-0.9 (L3 coherence point) +
//   barrier2 + coord load ~0.3 + inter-block skew ~0.3-0.5.
// Probed from both sides: participants (8..32 via r14/r15), poll topology
// (r5/r7/r10), intra-block ordering (r8 vs r13/r14), pipelining (r9/r12).
//
// Locked-in lessons (r2-r15):
//  - relaxed-only AGENT atomics; tag+payload in one 64-bit word (r7/r8:
//    agent acquire/release = chip-wide cache-maintenance storms).
//  - ONE relaxed polling wave per block; 256 pollers/16 slots optimal
//    (r5/r10/r15).
//  - hardware barrier beats software tag-spin intra-block (r13/r14).
//  - points in LDS SoA; allocator never keeps them register-resident (r3-r5).
//  - FMA-chain distance d = fma(dz,dz, fma(dy,dy, dx*dx)), subs exact-rounded
//    (r2: bit-exact vs reference trajectory).
//  - removals help; rearrangements, pipelining, added traffic regress.

#define BATCH 16
#define NPTS  131072
#define NSAMP 4096
#define NBLK  16                  // blocks per batch
#define TPB   1024                // 16 waves
#define CHUNK (NPTS / NBLK)       // 8192 points per block
#define PPT   (CHUNK / TPB)       // 8 points per thread
#define NWAVE (TPB / 64)

typedef unsigned long long u64;
typedef unsigned int u32;

// Global slot word (8B, one per block per parity):
//   [63:32] dist bits (>=0 -> monotone) | [31:15] idx (17b) | [14:0] iter tag
// Poison 0xAA.. -> tag 0x2AAA; zero-init -> tag 0; live tags are 1..4095.
// Ring-2 by parity; ordering via the value-dependence chain (r8-proven).

__global__ void fps_init_kernel(u64* __restrict__ ws) {
    int i = blockIdx.x * blockDim.x + threadIdx.x;
    if (i < BATCH * 2 * NBLK) ws[i] = 0ull;
}

__global__ __launch_bounds__(TPB, 4) void fps_kernel(
        const float* __restrict__ xyz, int* __restrict__ out,
        u64* __restrict__ gslot) {
    const int blk   = blockIdx.x;
    const int b     = blk & 15;    // batch: a batch's 16 blocks share blk%8
    const int chunk = blk >> 4;    //        -> same XCD (round-robin dispatch)
    const int tid   = threadIdx.x;
    const int w     = tid >> 6;
    const int lane  = tid & 63;

    const float* bxyz = xyz + (size_t)b * NPTS * 3;
    const int base = chunk * CHUNK;

    // ---- LDS: SoA points + plain red keys + plain bc (all barrier-ordered) --
    __shared__ float2 sxy[CHUNK];          // 64 KB
    __shared__ float  szz[CHUNK];          // 32 KB
    __shared__ u64 red[NWAVE];
    __shared__ u32 bc;                     // winning index, barrier-ordered
    for (int i = tid; i < CHUNK; i += TPB) {
        size_t p = (size_t)(base + i) * 3;
        sxy[i] = make_float2(bxyz[p + 0], bxyz[p + 1]);
        szz[i] = bxyz[p + 2];
    }
    if (tid == 0 && chunk == 0) out[b * NSAMP] = 0; // iter 0 emits index 0
    __syncthreads();   // staging visibility

    float pd[PPT];
#pragma unroll
    for (int k = 0; k < PPT; ++k) pd[k] = __builtin_inff();

    float cx = bxyz[0], cy = bxyz[1], cz = bxyz[2];

    u64* gs = gslot + (size_t)b * 2 * NBLK;   // [2][NBLK]

    for (int it = 1; it < NSAMP; ++it) {
        const int par = it & 1;
        u64* gsp = gs + par * NBLK;

        // ---- update min-dists + local argmax (LDS + registers) ----
        // Verified arithmetic (round 2, absmax 0): FMA-contracted
        //   d = fma(dz,dz, fma(dy,dy, dx*dx)), subs exact-rounded.
        float bd = -1.0f;
        int   bk = 0;
#pragma unroll
        for (int k = 0; k < PPT; ++k) {
            int i = tid + TPB * k;
            float2 xy = sxy[i];
            float  z  = szz[i];
            float dx = __fsub_rn(xy.x, cx);
            float dy = __fsub_rn(xy.y, cy);
            float dz = __fsub_rn(z,    cz);
            float d  = __builtin_fmaf(dz, dz,
                         __builtin_fmaf(dy, dy, __fmul_rn(dx, dx)));
            float nd = fminf(pd[k], d);
            pd[k] = nd;
            // strict >: earliest k wins (gi ascends with k) = first-occurrence
            if (nd > bd) { bd = nd; bk = k; }
        }
        u32 gi = (u32)(base + tid + TPB * bk);
        u64 key = ((u64)__float_as_uint(bd) << 32) | (u64)(~gi);

        // ---- wave butterfly (max dist, then min index) ----
#pragma unroll
        for (int off = 1; off <= 32; off <<= 1) {
            u64 o = __shfl_xor(key, off, 64);
            key = key > o ? key : o;
        }
        if (lane == 0) red[w] = key;      // plain store; barrier1 orders it
        __syncthreads();                   // barrier1 (replaced red tag-poll, r13)

        if (w == 0) {
            // ---- combine 16 plain keys (real keys > 0; lanes 16+ feed 0) ----
            u64 k2 = (lane < NWAVE) ? red[lane] : 0ull;
#pragma unroll
            for (int off = 1; off <= 8; off <<= 1) {
                u64 o = __shfl_xor(k2, off, 64);
                k2 = k2 > o ? k2 : o;
            }
            // ---- ONE relaxed agent store publishes the block winner ----
            if (lane == 0) {
                u32 db  = (u32)(k2 >> 32);
                u32 idx = ~(u32)k2;        // = gi (fits 17 bits)
                __hip_atomic_store(&gsp[chunk],
                                   ((u64)db << 32) | ((u64)idx << 15) | (u64)it,
                                   __ATOMIC_RELAXED, __HIP_MEMORY_SCOPE_AGENT);
            }
            // ---- relaxed poll of the 16 slot words (byte-identical to r8) ----
            u64 v; bool ok;
            do {
                v  = (lane < NBLK)
                       ? __hip_atomic_load(&gsp[lane], __ATOMIC_RELAXED,
                                           __HIP_MEMORY_SCOPE_AGENT)
                       : 0ull;
                ok = (lane < NBLK) ? ((v & 0x7FFFull) == (u64)it) : true;
            } while (__ballot(ok) != ~0ull);
            u64 k3 = 0ull;
            if (lane < NBLK) {
                u32 db  = (u32)(v >> 32);
                u32 idx = (u32)((v >> 15) & 0x1FFFFu);
                k3 = ((u64)db << 32) | (u64)(~idx);
            }
            // 4-step butterfly: lanes 0..15 are a closed hypercube; then
            // broadcast lane0's winner to the whole wave.
#pragma unroll
            for (int off = 1; off <= 8; off <<= 1) {
                u64 o = __shfl_xor(k3, off, 64);
                k3 = k3 > o ? k3 : o;
            }
            k3 = __shfl(k3, 0, 64);
            u32 widx = ~(u32)k3;
            if (lane == 0) {
                if (chunk == 0) out[b * NSAMP + it] = (int)widx;
                bc = widx;                 // plain store; barrier2 orders it
            }
        }
        __syncthreads();                   // barrier2 (replaces the bc tag-spin)

        u32 widx = bc;                     // barrier-ordered plain read
        cx = bxyz[3 * (size_t)widx + 0];   // same-address broadcast load
        cy = bxyz[3 * (size_t)widx + 1];
        cz = bxyz[3 * (size_t)widx + 2];
    }
}

extern "C" void kernel_launch(void* const* d_in, const int* in_sizes, int n_in,
                              void* d_out, int out_size, void* d_ws, size_t ws_size,
                              hipStream_t stream) {
    const float* xyz = (const float*)d_in[0];
    int* out = (int*)d_out;
    u64* gslot = (u64*)d_ws;   // [BATCH][2][NBLK] u64 = 4 KB

    hipLaunchKernelGGL(fps_init_kernel, dim3(1), dim3(512), 0, stream, gslot);
    hipLaunchKernelGGL(fps_kernel, dim3(BATCH * NBLK), dim3(TPB), 0, stream,
                       xyz, out, gslot);
}